// Round 1
// 1276.433 us; speedup vs baseline: 1.0166x; 1.0166x over previous
//
#include <hip/hip_runtime.h>
#include <hip/hip_bf16.h>
#include <math.h>

#define F 602
#define C 41
#define HP_STRIDE 64   // bf16 h row padded to 64 elems (128 B): 1 aligned line per gather
#define KSTEPS 19      // ceil(602/32)
#define GROWS 64       // gemm rows per block
#define ASTRIDE 616    // LDS row stride in u16: 308 dwords -> 20 mod 32 -> 2-way (free)

typedef short short8 __attribute__((ext_vector_type(8)));
typedef float f32x4 __attribute__((ext_vector_type(4)));

static __device__ __forceinline__ unsigned short f2bf(float f){
  unsigned int x = __float_as_uint(f);
  x += 0x7FFFu + ((x >> 16) & 1u);   // RNE; no NaNs in this workload
  return (unsigned short)(x >> 16);
}
static __device__ __forceinline__ float bf2f(unsigned short u){
  return __uint_as_float(((unsigned int)u) << 16);
}

// edge_index may arrive as int64 (reference dtype) or int32 (harness doc).
// Detect on-device: if int64 (little-endian), all high words are 0.
__global__ void k_flag(const int* __restrict__ e32, int* __restrict__ flag){
  __shared__ int s[256];
  int t = threadIdx.x;
  int v = 0;
  for (int i = t; i < 2048; i += 256) v |= e32[2*i + 1];
  s[t] = v; __syncthreads();
  for (int off = 128; off > 0; off >>= 1){
    if (t < off) s[t] |= s[t + off];
    __syncthreads();
  }
  if (t == 0) flag[0] = (s[0] == 0) ? 1 : 0;   // 1 => int64
}

static __device__ __forceinline__ int eidx(const int* __restrict__ p, int is64, long long pos){
  return is64 ? p[2*pos] : p[pos];   // low word (values < 2^31, non-negative)
}

__global__ void k_count(const int* __restrict__ ei, const int* __restrict__ flag,
                        int* __restrict__ count, int E){
  int e = blockIdx.x * 256 + threadIdx.x;
  if (e >= E) return;
  int is64 = flag[0];
  int d = eidx(ei, is64, (long long)E + e);
  atomicAdd(&count[d], 1);
}

// block scans 2048 counts (8/thread); also computes dinv = rsqrt(indeg+1)
__global__ void k_scan1(const int* __restrict__ count, int* __restrict__ rs,
                        float* __restrict__ dinv, int* __restrict__ bsum, int N){
  __shared__ int s[256];
  int t = threadIdx.x;
  int base = blockIdx.x * 2048 + t * 8;
  int v[8]; int tot = 0;
  #pragma unroll
  for (int j = 0; j < 8; j++){
    int i = base + j;
    int c = (i < N) ? count[i] : 0;
    v[j] = c; tot += c;
    if (i < N) dinv[i] = rsqrtf((float)(c + 1));
  }
  s[t] = tot; __syncthreads();
  for (int off = 1; off < 256; off <<= 1){
    int x = (t >= off) ? s[t - off] : 0;
    __syncthreads();
    s[t] += x;
    __syncthreads();
  }
  int run = s[t] - tot;  // exclusive prefix of this thread
  #pragma unroll
  for (int j = 0; j < 8; j++){
    int i = base + j;
    if (i < N) rs[i] = run;
    run += v[j];
  }
  if (t == 255) bsum[blockIdx.x] = s[255];
}

__global__ void k_scan2(int* __restrict__ bsum, int nb){
  __shared__ int s[256];
  int t = threadIdx.x;
  int v = (t < nb) ? bsum[t] : 0;
  s[t] = v; __syncthreads();
  for (int off = 1; off < 256; off <<= 1){
    int x = (t >= off) ? s[t - off] : 0;
    __syncthreads();
    s[t] += x;
    __syncthreads();
  }
  if (t < nb) bsum[t] = s[t] - v;   // exclusive
}

__global__ void k_scan3(int* __restrict__ rs, int* __restrict__ cur,
                        const int* __restrict__ bsum, int N, int E){
  int i = blockIdx.x * 256 + threadIdx.x;
  if (i == 0) rs[N] = E;
  if (i >= N) return;
  int r = rs[i] + bsum[i >> 11];
  rs[i] = r; cur[i] = r;
}

// csr holds src only (4 B/edge); norm recomputed in k_agg from dinv.
__global__ void k_fill(const int* __restrict__ ei, const int* __restrict__ flag,
                       int* __restrict__ cur, int* __restrict__ csr, int E){
  int e = blockIdx.x * 256 + threadIdx.x;
  if (e >= E) return;
  int is64 = flag[0];
  int s = eidx(ei, is64, e);
  int d = eidx(ei, is64, (long long)E + e);
  int pos = atomicAdd(&cur[d], 1);
  csr[pos] = s;
}

// Pre-swizzle W (fp32 [602][41]) into bf16 B-fragment layout for
// mfma_f32_16x16x32_bf16: Wf[((s*3+nt)*64+lane)*8 + j] = W[k=s*32+quad*8+j][n=nt*16+l16]
__global__ void k_wprep(const float* __restrict__ W, unsigned short* __restrict__ Wf){
  int idx = blockIdx.x * 256 + threadIdx.x;
  if (idx >= KSTEPS * 3 * 64) return;
  int lane = idx & 63;
  int nt = (idx >> 6) % 3;
  int s = idx / (3 * 64);
  int quad = lane >> 4, l16 = lane & 15;
  int n = nt * 16 + l16;
  unsigned int w[4];
  #pragma unroll
  for (int p = 0; p < 4; p++){
    int k0 = s * 32 + quad * 8 + 2 * p;
    float lo = (k0     < F && n < C) ? W[k0 * C + n]       : 0.f;
    float hi = (k0 + 1 < F && n < C) ? W[(k0 + 1) * C + n] : 0.f;
    w[p] = (unsigned)f2bf(lo) | ((unsigned)f2bf(hi) << 16);
  }
  ((uint4*)Wf)[idx] = make_uint4(w[0], w[1], w[2], w[3]);
}

// MFMA GEMM v3: stage the ENTIRE contiguous 64-row x-tile (154 KB) into LDS
// with flat coalesced float4 loads, ONE barrier, then 19 MFMA K-steps from LDS.
// Wave w owns 16 rows x 48 cols (3 N-tiles). W-frags from the 58 KB L1-hot table.
__global__ __launch_bounds__(256) void k_gemm3(const float* __restrict__ x,
        const unsigned short* __restrict__ Wf, unsigned short* __restrict__ hp, int N){
  __shared__ unsigned short As[GROWS * ASTRIDE];
  const int t = threadIdx.x;
  const long long rb0 = (long long)blockIdx.x * GROWS;
  // ---- zero the K-tail (cols 602..607 feed the s=18 MFMA; must not be NaN) ----
  for (int i = t; i < GROWS * 6; i += 256){
    int r = i / 6, c = 602 + (i - r * 6);
    As[r * ASTRIDE + c] = 0;
  }
  // ---- stage: flat coalesced float4 over the contiguous tile ----
  long long nrow = (long long)N - rb0; if (nrow > GROWS) nrow = GROWS;
  const int limit = (int)(nrow * F);              // floats in tile (38528 full)
  const float* base = x + rb0 * F;                // 16B-aligned (rb0 even)
  #pragma unroll 4
  for (int f4 = t; f4 * 4 < limit; f4 += 256){
    int idx = f4 * 4;
    float4 v = *(const float4*)(base + idx);
    int row = idx / F;                            // magic-mul division
    int col = idx - row * F;
    if (col <= F - 4){                            // fast path: single row
      int a = row * ASTRIDE + col;                // col even -> a even
      unsigned p0 = (unsigned)f2bf(v.x) | ((unsigned)f2bf(v.y) << 16);
      unsigned p1 = (unsigned)f2bf(v.z) | ((unsigned)f2bf(v.w) << 16);
      *(unsigned*)&As[a]     = p0;
      *(unsigned*)&As[a + 2] = p1;
    } else {                                      // straddles a row boundary
      float e[4] = {v.x, v.y, v.z, v.w};
      #pragma unroll
      for (int q = 0; q < 4; q++){
        int ii = idx + q;
        int r2 = ii / F, c2 = ii - r2 * F;
        As[r2 * ASTRIDE + c2] = f2bf(e[q]);
      }
    }
  }
  __syncthreads();
  // ---- compute: wave w -> rows [w*16, w*16+16), 3 N-tiles, 19 K-steps ----
  const int wv = t >> 6, lane = t & 63;
  const int quad = lane >> 4, l16 = lane & 15;
  const unsigned short* arow = &As[(wv * 16 + l16) * ASTRIDE + quad * 8];
  const short8* wf8 = (const short8*)Wf;
  f32x4 acc0 = {0.f,0.f,0.f,0.f}, acc1 = acc0, acc2 = acc0;
  #pragma unroll
  for (int s = 0; s < KSTEPS; s++){
    short8 a  = *(const short8*)(arow + s * 32);
    short8 b0 = wf8[(s * 3 + 0) * 64 + lane];
    short8 b1 = wf8[(s * 3 + 1) * 64 + lane];
    short8 b2 = wf8[(s * 3 + 2) * 64 + lane];
    acc0 = __builtin_amdgcn_mfma_f32_16x16x32_bf16(a, b0, acc0, 0, 0, 0);
    acc1 = __builtin_amdgcn_mfma_f32_16x16x32_bf16(a, b1, acc1, 0, 0, 0);
    acc2 = __builtin_amdgcn_mfma_f32_16x16x32_bf16(a, b2, acc2, 0, 0, 0);
  }
  // epilogue: C/D layout col=lane&15, row=quad*4+reg  [m89-verified]
  int rl = wv * 16 + quad * 4;
  #pragma unroll
  for (int reg = 0; reg < 4; reg++){
    long long grow = rb0 + rl + reg;
    if (grow < N){
      unsigned short* hr = hp + grow * HP_STRIDE;
      hr[0 * 16 + l16] = f2bf(acc0[reg]);
      hr[1 * 16 + l16] = f2bf(acc1[reg]);
      hr[2 * 16 + l16] = f2bf(acc2[reg]);
    }
  }
}

// one wave per node; lanes 0..40 = classes. Gather h[src] rows (1 aligned
// 128-B line each), fp32 accumulate, then FUSED bias + log_softmax epilogue.
// norm = dinv[src]*dinv[dst] recomputed here (dinv is 800 KB, L2-resident).
__global__ __launch_bounds__(256) void k_agg(const unsigned short* __restrict__ hp,
        const int* __restrict__ csr, const int* __restrict__ rs,
        const float* __restrict__ dinv, const float* __restrict__ b,
        float* __restrict__ agg, float* __restrict__ z, int N){
  int node = blockIdx.x * 4 + (threadIdx.x >> 6);
  int lane = threadIdx.x & 63;
  if (node >= N) return;
  int beg = rs[node], end = rs[node + 1];
  float dn = dinv[node];
  bool act = lane < C;
  const unsigned short* hb = hp + lane;           // row r at hb[r<<6]
  float acc = 0.f;
  if (act) acc = dn * dn * bf2f(hb[(long long)node << 6]);  // self-loop
  int i = beg;
  for (; i + 7 < end; i += 8){
    int s0 = csr[i],   s1 = csr[i+1], s2 = csr[i+2], s3 = csr[i+3];
    int s4 = csr[i+4], s5 = csr[i+5], s6 = csr[i+6], s7 = csr[i+7];
    float n0 = dinv[s0] * dn, n1 = dinv[s1] * dn;
    float n2 = dinv[s2] * dn, n3 = dinv[s3] * dn;
    float n4 = dinv[s4] * dn, n5 = dinv[s5] * dn;
    float n6 = dinv[s6] * dn, n7 = dinv[s7] * dn;
    float h0 = 0.f, h1 = 0.f, h2 = 0.f, h3 = 0.f;
    float h4 = 0.f, h5 = 0.f, h6 = 0.f, h7 = 0.f;
    if (act){
      h0 = bf2f(hb[(long long)s0 << 6]);
      h1 = bf2f(hb[(long long)s1 << 6]);
      h2 = bf2f(hb[(long long)s2 << 6]);
      h3 = bf2f(hb[(long long)s3 << 6]);
      h4 = bf2f(hb[(long long)s4 << 6]);
      h5 = bf2f(hb[(long long)s5 << 6]);
      h6 = bf2f(hb[(long long)s6 << 6]);
      h7 = bf2f(hb[(long long)s7 << 6]);
    }
    acc = fmaf(n0, h0, acc); acc = fmaf(n1, h1, acc);
    acc = fmaf(n2, h2, acc); acc = fmaf(n3, h3, acc);
    acc = fmaf(n4, h4, acc); acc = fmaf(n5, h5, acc);
    acc = fmaf(n6, h6, acc); acc = fmaf(n7, h7, acc);
  }
  for (; i + 3 < end; i += 4){
    int s0 = csr[i], s1 = csr[i+1], s2 = csr[i+2], s3 = csr[i+3];
    float n0 = dinv[s0] * dn, n1 = dinv[s1] * dn;
    float n2 = dinv[s2] * dn, n3 = dinv[s3] * dn;
    float h0 = 0.f, h1 = 0.f, h2 = 0.f, h3 = 0.f;
    if (act){
      h0 = bf2f(hb[(long long)s0 << 6]);
      h1 = bf2f(hb[(long long)s1 << 6]);
      h2 = bf2f(hb[(long long)s2 << 6]);
      h3 = bf2f(hb[(long long)s3 << 6]);
    }
    acc = fmaf(n0, h0, acc); acc = fmaf(n1, h1, acc);
    acc = fmaf(n2, h2, acc); acc = fmaf(n3, h3, acc);
  }
  for (; i < end; i++){
    int s0 = csr[i];
    float n0 = dinv[s0] * dn;
    if (act) acc = fmaf(n0, bf2f(hb[(long long)s0 << 6]), acc);
  }
  // ---- fused epilogue: bias, agg write, log_softmax, z write ----
  float a = -3.0e38f;
  if (act){
    a = acc + b[lane];
    agg[(long long)node * C + lane] = a;
  }
  float m = a;
  #pragma unroll
  for (int off = 32; off > 0; off >>= 1) m = fmaxf(m, __shfl_xor(m, off, 64));
  float ex = act ? expf(a - m) : 0.f;
  float s = ex;
  #pragma unroll
  for (int off = 32; off > 0; off >>= 1) s += __shfl_xor(s, off, 64);
  if (act) z[(long long)node * C + lane] = a - m - logf(s);
}

extern "C" void kernel_launch(void* const* d_in, const int* in_sizes, int n_in,
                              void* d_out, int out_size, void* d_ws, size_t ws_size,
                              hipStream_t stream){
  const float* x = (const float*)d_in[0];
  const float* W = (const float*)d_in[1];
  const float* b = (const float*)d_in[2];
  const int*   ei = (const int*)d_in[3];
  int N = in_sizes[0] / F;   // 200000
  int E = in_sizes[3] / 2;   // 3200000

  float* out = (float*)d_out;
  float* agg = out;
  float* z   = out + (long long)N * C;

  char* ws = (char*)d_ws;
  auto al = [](size_t v){ return (v + 255) & ~size_t(255); };
  size_t o = 0;
  int*   flag  = (int*)(ws + o);  o = al(o + 4);
  int*   count = (int*)(ws + o);  o = al(o + (size_t)N * 4);
  float* dinv  = (float*)(ws + o); o = al(o + (size_t)N * 4);
  int*   rs    = (int*)(ws + o);  o = al(o + ((size_t)N + 1) * 4);
  int*   cur   = (int*)(ws + o);  o = al(o + (size_t)N * 4);
  int*   bsum  = (int*)(ws + o);  o = al(o + 4096);
  unsigned short* Wf = (unsigned short*)(ws + o); o = al(o + (size_t)KSTEPS * 3 * 64 * 16);
  int*   csr   = (int*)(ws + o);  o = al(o + (size_t)E * 4);
  // hp now lives in workspace (25.6 MB) so z can be written while hp is read
  unsigned short* hp = (unsigned short*)(ws + o); o = al(o + (size_t)N * HP_STRIDE * 2);

  int nb_e    = (E + 255) / 256;
  int nb_scan = (N + 2047) / 2048;
  int nb_n    = (N + 255) / 256;
  int nb_g    = (N + GROWS - 1) / GROWS;
  int nb_node = (N + 3) / 4;
  int nb_w    = (KSTEPS * 3 * 64 + 255) / 256;

  k_flag<<<1, 256, 0, stream>>>(ei, flag);
  hipMemsetAsync(count, 0, (size_t)N * 4, stream);
  k_count<<<nb_e, 256, 0, stream>>>(ei, flag, count, E);
  k_wprep<<<nb_w, 256, 0, stream>>>(W, Wf);
  k_scan1<<<nb_scan, 256, 0, stream>>>(count, rs, dinv, bsum, N);
  k_scan2<<<1, 256, 0, stream>>>(bsum, nb_scan);
  k_scan3<<<nb_n, 256, 0, stream>>>(rs, cur, bsum, N, E);
  k_fill<<<nb_e, 256, 0, stream>>>(ei, flag, cur, csr, E);
  k_gemm3<<<nb_g, 256, 0, stream>>>(x, Wf, hp, N);
  k_agg<<<nb_node, 256, 0, stream>>>(hp, csr, rs, dinv, b, agg, z, N);
}

// Round 2
// 1082.982 us; speedup vs baseline: 1.1982x; 1.1786x over previous
//
#include <hip/hip_runtime.h>
#include <hip/hip_bf16.h>
#include <math.h>

#define F 602
#define C 41
#define HP_STRIDE 64   // bf16 h row padded to 64 elems (128 B): 1 aligned line per gather
#define KSTEPS 19      // ceil(602/32)
#define GROWS 64       // gemm rows per block
#define ASTRIDE 616    // LDS row stride in u16: 308 dwords -> 20 mod 32 -> 2-way (free)

typedef short short8 __attribute__((ext_vector_type(8)));
typedef float f32x4 __attribute__((ext_vector_type(4)));

static __device__ __forceinline__ unsigned short f2bf(float f){
  unsigned int x = __float_as_uint(f);
  x += 0x7FFFu + ((x >> 16) & 1u);   // RNE; no NaNs in this workload
  return (unsigned short)(x >> 16);
}
static __device__ __forceinline__ float bf2f(unsigned short u){
  return __uint_as_float(((unsigned int)u) << 16);
}

// edge_index may arrive as int64 (reference dtype) or int32 (harness doc).
// Detect on-device: if int64 (little-endian), all high words are 0.
__global__ void k_flag(const int* __restrict__ e32, int* __restrict__ flag){
  __shared__ int s[256];
  int t = threadIdx.x;
  int v = 0;
  for (int i = t; i < 2048; i += 256) v |= e32[2*i + 1];
  s[t] = v; __syncthreads();
  for (int off = 128; off > 0; off >>= 1){
    if (t < off) s[t] |= s[t + off];
    __syncthreads();
  }
  if (t == 0) flag[0] = (s[0] == 0) ? 1 : 0;   // 1 => int64
}

static __device__ __forceinline__ int eidx(const int* __restrict__ p, int is64, long long pos){
  return is64 ? p[2*pos] : p[pos];   // low word (values < 2^31, non-negative)
}

// ONE atomic pass: returning atomicAdd gives both the degree histogram and
// this edge's slot within its destination's CSR segment (epos).
__global__ void k_count(const int* __restrict__ ei, const int* __restrict__ flag,
                        int* __restrict__ count, int* __restrict__ epos, int E){
  int e = blockIdx.x * 256 + threadIdx.x;
  if (e >= E) return;
  int is64 = flag[0];
  int d = eidx(ei, is64, (long long)E + e);
  epos[e] = atomicAdd(&count[d], 1);
}

// block scans 2048 counts (8/thread); also computes dinv = rsqrt(indeg+1)
__global__ void k_scan1(const int* __restrict__ count, int* __restrict__ rs,
                        float* __restrict__ dinv, int* __restrict__ bsum, int N){
  __shared__ int s[256];
  int t = threadIdx.x;
  int base = blockIdx.x * 2048 + t * 8;
  int v[8]; int tot = 0;
  #pragma unroll
  for (int j = 0; j < 8; j++){
    int i = base + j;
    int c = (i < N) ? count[i] : 0;
    v[j] = c; tot += c;
    if (i < N) dinv[i] = rsqrtf((float)(c + 1));
  }
  s[t] = tot; __syncthreads();
  for (int off = 1; off < 256; off <<= 1){
    int x = (t >= off) ? s[t - off] : 0;
    __syncthreads();
    s[t] += x;
    __syncthreads();
  }
  int run = s[t] - tot;  // exclusive prefix of this thread
  #pragma unroll
  for (int j = 0; j < 8; j++){
    int i = base + j;
    if (i < N) rs[i] = run;
    run += v[j];
  }
  if (t == 255) bsum[blockIdx.x] = s[255];
}

__global__ void k_scan2(int* __restrict__ bsum, int nb){
  __shared__ int s[256];
  int t = threadIdx.x;
  int v = (t < nb) ? bsum[t] : 0;
  s[t] = v; __syncthreads();
  for (int off = 1; off < 256; off <<= 1){
    int x = (t >= off) ? s[t - off] : 0;
    __syncthreads();
    s[t] += x;
    __syncthreads();
  }
  if (t < nb) bsum[t] = s[t] - v;   // exclusive
}

__global__ void k_scan3(int* __restrict__ rs, const int* __restrict__ bsum, int N, int E){
  int i = blockIdx.x * 256 + threadIdx.x;
  if (i == 0) rs[N] = E;
  if (i >= N) return;
  rs[i] = rs[i] + bsum[i >> 11];
}

// csr holds src only (4 B/edge); slot = rs[d] + epos[e] -- NO atomics here.
__global__ void k_fill(const int* __restrict__ ei, const int* __restrict__ flag,
                       const int* __restrict__ epos, const int* __restrict__ rs,
                       int* __restrict__ csr, int E){
  int e = blockIdx.x * 256 + threadIdx.x;
  if (e >= E) return;
  int is64 = flag[0];
  int s = eidx(ei, is64, e);
  int d = eidx(ei, is64, (long long)E + e);
  csr[rs[d] + epos[e]] = s;
}

// Pre-swizzle W (fp32 [602][41]) into bf16 B-fragment layout for
// mfma_f32_16x16x32_bf16: Wf[((s*3+nt)*64+lane)*8 + j] = W[k=s*32+quad*8+j][n=nt*16+l16]
__global__ void k_wprep(const float* __restrict__ W, unsigned short* __restrict__ Wf){
  int idx = blockIdx.x * 256 + threadIdx.x;
  if (idx >= KSTEPS * 3 * 64) return;
  int lane = idx & 63;
  int nt = (idx >> 6) % 3;
  int s = idx / (3 * 64);
  int quad = lane >> 4, l16 = lane & 15;
  int n = nt * 16 + l16;
  unsigned int w[4];
  #pragma unroll
  for (int p = 0; p < 4; p++){
    int k0 = s * 32 + quad * 8 + 2 * p;
    float lo = (k0     < F && n < C) ? W[k0 * C + n]       : 0.f;
    float hi = (k0 + 1 < F && n < C) ? W[(k0 + 1) * C + n] : 0.f;
    w[p] = (unsigned)f2bf(lo) | ((unsigned)f2bf(hi) << 16);
  }
  ((uint4*)Wf)[idx] = make_uint4(w[0], w[1], w[2], w[3]);
}

// MFMA GEMM v3: stage the ENTIRE contiguous 64-row x-tile (154 KB) into LDS
// with flat coalesced nontemporal float4 loads (x is read exactly once --
// don't evict the L2-resident Wf/rs/dinv/hp working set), ONE barrier, then
// 19 MFMA K-steps from LDS. Wave w owns 16 rows x 48 cols (3 N-tiles).
__global__ __launch_bounds__(256) void k_gemm3(const float* __restrict__ x,
        const unsigned short* __restrict__ Wf, unsigned short* __restrict__ hp, int N){
  __shared__ unsigned short As[GROWS * ASTRIDE];
  const int t = threadIdx.x;
  const long long rb0 = (long long)blockIdx.x * GROWS;
  // ---- zero the K-tail (cols 602..607 feed the s=18 MFMA; must not be NaN) ----
  for (int i = t; i < GROWS * 6; i += 256){
    int r = i / 6, c = 602 + (i - r * 6);
    As[r * ASTRIDE + c] = 0;
  }
  // ---- stage: flat coalesced float4 over the contiguous tile ----
  long long nrow = (long long)N - rb0; if (nrow > GROWS) nrow = GROWS;
  const int limit = (int)(nrow * F);              // floats in tile (38528 full)
  const float* base = x + rb0 * F;                // 16B-aligned (rb0 even)
  #pragma unroll 8
  for (int f4 = t; f4 * 4 < limit; f4 += 256){
    int idx = f4 * 4;
    f32x4 v = __builtin_nontemporal_load((const f32x4*)(base + idx));
    int row = idx / F;                            // magic-mul division
    int col = idx - row * F;
    if (col <= F - 4){                            // fast path: single row
      int a = row * ASTRIDE + col;                // col even -> a even
      unsigned p0 = (unsigned)f2bf(v[0]) | ((unsigned)f2bf(v[1]) << 16);
      unsigned p1 = (unsigned)f2bf(v[2]) | ((unsigned)f2bf(v[3]) << 16);
      *(unsigned*)&As[a]     = p0;
      *(unsigned*)&As[a + 2] = p1;
    } else {                                      // straddles a row boundary
      float e[4] = {v[0], v[1], v[2], v[3]};
      #pragma unroll
      for (int q = 0; q < 4; q++){
        int ii = idx + q;
        int r2 = ii / F, c2 = ii - r2 * F;
        As[r2 * ASTRIDE + c2] = f2bf(e[q]);
      }
    }
  }
  __syncthreads();
  // ---- compute: wave w -> rows [w*16, w*16+16), 3 N-tiles, 19 K-steps ----
  const int wv = t >> 6, lane = t & 63;
  const int quad = lane >> 4, l16 = lane & 15;
  const unsigned short* arow = &As[(wv * 16 + l16) * ASTRIDE + quad * 8];
  const short8* wf8 = (const short8*)Wf;
  f32x4 acc0 = {0.f,0.f,0.f,0.f}, acc1 = acc0, acc2 = acc0;
  #pragma unroll
  for (int s = 0; s < KSTEPS; s++){
    short8 a  = *(const short8*)(arow + s * 32);
    short8 b0 = wf8[(s * 3 + 0) * 64 + lane];
    short8 b1 = wf8[(s * 3 + 1) * 64 + lane];
    short8 b2 = wf8[(s * 3 + 2) * 64 + lane];
    acc0 = __builtin_amdgcn_mfma_f32_16x16x32_bf16(a, b0, acc0, 0, 0, 0);
    acc1 = __builtin_amdgcn_mfma_f32_16x16x32_bf16(a, b1, acc1, 0, 0, 0);
    acc2 = __builtin_amdgcn_mfma_f32_16x16x32_bf16(a, b2, acc2, 0, 0, 0);
  }
  // epilogue: C/D layout col=lane&15, row=quad*4+reg  [m89-verified]
  int rl = wv * 16 + quad * 4;
  #pragma unroll
  for (int reg = 0; reg < 4; reg++){
    long long grow = rb0 + rl + reg;
    if (grow < N){
      unsigned short* hr = hp + grow * HP_STRIDE;
      hr[0 * 16 + l16] = f2bf(acc0[reg]);
      hr[1 * 16 + l16] = f2bf(acc1[reg]);
      hr[2 * 16 + l16] = f2bf(acc2[reg]);
    }
  }
}

// one wave per node; lanes 0..40 = classes. Gather h[src] rows (1 aligned
// 128-B line each), fp32 accumulate, then FUSED bias + log_softmax epilogue.
// norm = dinv[src]*dinv[dst] recomputed here (dinv is 800 KB, L2-resident).
__global__ __launch_bounds__(256) void k_agg(const unsigned short* __restrict__ hp,
        const int* __restrict__ csr, const int* __restrict__ rs,
        const float* __restrict__ dinv, const float* __restrict__ b,
        float* __restrict__ agg, float* __restrict__ z, int N){
  int node = blockIdx.x * 4 + (threadIdx.x >> 6);
  int lane = threadIdx.x & 63;
  if (node >= N) return;
  int beg = rs[node], end = rs[node + 1];
  float dn = dinv[node];
  bool act = lane < C;
  const unsigned short* hb = hp + lane;           // row r at hb[r<<6]
  float acc = 0.f;
  if (act) acc = dn * dn * bf2f(hb[(long long)node << 6]);  // self-loop
  int i = beg;
  for (; i + 7 < end; i += 8){
    int s0 = csr[i],   s1 = csr[i+1], s2 = csr[i+2], s3 = csr[i+3];
    int s4 = csr[i+4], s5 = csr[i+5], s6 = csr[i+6], s7 = csr[i+7];
    float n0 = dinv[s0] * dn, n1 = dinv[s1] * dn;
    float n2 = dinv[s2] * dn, n3 = dinv[s3] * dn;
    float n4 = dinv[s4] * dn, n5 = dinv[s5] * dn;
    float n6 = dinv[s6] * dn, n7 = dinv[s7] * dn;
    float h0 = 0.f, h1 = 0.f, h2 = 0.f, h3 = 0.f;
    float h4 = 0.f, h5 = 0.f, h6 = 0.f, h7 = 0.f;
    if (act){
      h0 = bf2f(hb[(long long)s0 << 6]);
      h1 = bf2f(hb[(long long)s1 << 6]);
      h2 = bf2f(hb[(long long)s2 << 6]);
      h3 = bf2f(hb[(long long)s3 << 6]);
      h4 = bf2f(hb[(long long)s4 << 6]);
      h5 = bf2f(hb[(long long)s5 << 6]);
      h6 = bf2f(hb[(long long)s6 << 6]);
      h7 = bf2f(hb[(long long)s7 << 6]);
    }
    acc = fmaf(n0, h0, acc); acc = fmaf(n1, h1, acc);
    acc = fmaf(n2, h2, acc); acc = fmaf(n3, h3, acc);
    acc = fmaf(n4, h4, acc); acc = fmaf(n5, h5, acc);
    acc = fmaf(n6, h6, acc); acc = fmaf(n7, h7, acc);
  }
  for (; i + 3 < end; i += 4){
    int s0 = csr[i], s1 = csr[i+1], s2 = csr[i+2], s3 = csr[i+3];
    float n0 = dinv[s0] * dn, n1 = dinv[s1] * dn;
    float n2 = dinv[s2] * dn, n3 = dinv[s3] * dn;
    float h0 = 0.f, h1 = 0.f, h2 = 0.f, h3 = 0.f;
    if (act){
      h0 = bf2f(hb[(long long)s0 << 6]);
      h1 = bf2f(hb[(long long)s1 << 6]);
      h2 = bf2f(hb[(long long)s2 << 6]);
      h3 = bf2f(hb[(long long)s3 << 6]);
    }
    acc = fmaf(n0, h0, acc); acc = fmaf(n1, h1, acc);
    acc = fmaf(n2, h2, acc); acc = fmaf(n3, h3, acc);
  }
  for (; i < end; i++){
    int s0 = csr[i];
    float n0 = dinv[s0] * dn;
    if (act) acc = fmaf(n0, bf2f(hb[(long long)s0 << 6]), acc);
  }
  // ---- fused epilogue: bias, agg write, log_softmax, z write ----
  float a = -3.0e38f;
  if (act){
    a = acc + b[lane];
    agg[(long long)node * C + lane] = a;
  }
  float m = a;
  #pragma unroll
  for (int off = 32; off > 0; off >>= 1) m = fmaxf(m, __shfl_xor(m, off, 64));
  float ex = act ? expf(a - m) : 0.f;
  float s = ex;
  #pragma unroll
  for (int off = 32; off > 0; off >>= 1) s += __shfl_xor(s, off, 64);
  if (act) z[(long long)node * C + lane] = a - m - logf(s);
}

extern "C" void kernel_launch(void* const* d_in, const int* in_sizes, int n_in,
                              void* d_out, int out_size, void* d_ws, size_t ws_size,
                              hipStream_t stream){
  const float* x = (const float*)d_in[0];
  const float* W = (const float*)d_in[1];
  const float* b = (const float*)d_in[2];
  const int*   ei = (const int*)d_in[3];
  int N = in_sizes[0] / F;   // 200000
  int E = in_sizes[3] / 2;   // 3200000

  float* out = (float*)d_out;
  float* agg = out;
  float* z   = out + (long long)N * C;

  char* ws = (char*)d_ws;
  auto al = [](size_t v){ return (v + 255) & ~size_t(255); };
  size_t o = 0;
  int*   flag  = (int*)(ws + o);  o = al(o + 4);
  int*   count = (int*)(ws + o);  o = al(o + (size_t)N * 4);
  float* dinv  = (float*)(ws + o); o = al(o + (size_t)N * 4);
  int*   rs    = (int*)(ws + o);  o = al(o + ((size_t)N + 1) * 4);
  int*   bsum  = (int*)(ws + o);  o = al(o + 4096);
  unsigned short* Wf = (unsigned short*)(ws + o); o = al(o + (size_t)KSTEPS * 3 * 64 * 16);
  int*   epos  = (int*)(ws + o);  o = al(o + (size_t)E * 4);
  int*   csr   = (int*)(ws + o);  o = al(o + (size_t)E * 4);
  unsigned short* hp = (unsigned short*)(ws + o); o = al(o + (size_t)N * HP_STRIDE * 2);

  int nb_e    = (E + 255) / 256;
  int nb_scan = (N + 2047) / 2048;
  int nb_n    = (N + 255) / 256;
  int nb_g    = (N + GROWS - 1) / GROWS;
  int nb_node = (N + 3) / 4;
  int nb_w    = (KSTEPS * 3 * 64 + 255) / 256;

  k_flag<<<1, 256, 0, stream>>>(ei, flag);
  hipMemsetAsync(count, 0, (size_t)N * 4, stream);
  k_count<<<nb_e, 256, 0, stream>>>(ei, flag, count, epos, E);
  k_wprep<<<nb_w, 256, 0, stream>>>(W, Wf);
  k_scan1<<<nb_scan, 256, 0, stream>>>(count, rs, dinv, bsum, N);
  k_scan2<<<1, 256, 0, stream>>>(bsum, nb_scan);
  k_scan3<<<nb_n, 256, 0, stream>>>(rs, bsum, N, E);
  k_fill<<<nb_e, 256, 0, stream>>>(ei, flag, epos, rs, csr, E);
  k_gemm3<<<nb_g, 256, 0, stream>>>(x, Wf, hp, N);
  k_agg<<<nb_node, 256, 0, stream>>>(hp, csr, rs, dinv, b, agg, z, N);
}

// Round 3
// 1076.245 us; speedup vs baseline: 1.2057x; 1.0063x over previous
//
#include <hip/hip_runtime.h>
#include <hip/hip_bf16.h>
#include <math.h>

#define F 602
#define C 41
#define HP_STRIDE 64   // bf16 h row padded to 64 elems (128 B): 1 aligned line per gather
#define KSTEPS 19      // ceil(602/32)
#define GROWS 64       // gemm rows per block (4 waves x 16 rows)

typedef short short8 __attribute__((ext_vector_type(8)));
typedef float f32x4 __attribute__((ext_vector_type(4)));
typedef float f32x2 __attribute__((ext_vector_type(2)));

static __device__ __forceinline__ unsigned short f2bf(float f){
  unsigned int x = __float_as_uint(f);
  x += 0x7FFFu + ((x >> 16) & 1u);   // RNE; no NaNs in this workload
  return (unsigned short)(x >> 16);
}
static __device__ __forceinline__ float bf2f(unsigned short u){
  return __uint_as_float(((unsigned int)u) << 16);
}

// edge_index may arrive as int64 (reference dtype) or int32 (harness doc).
// Detect on-device: if int64 (little-endian), all high words are 0.
__global__ void k_flag(const int* __restrict__ e32, int* __restrict__ flag){
  __shared__ int s[256];
  int t = threadIdx.x;
  int v = 0;
  for (int i = t; i < 2048; i += 256) v |= e32[2*i + 1];
  s[t] = v; __syncthreads();
  for (int off = 128; off > 0; off >>= 1){
    if (t < off) s[t] |= s[t + off];
    __syncthreads();
  }
  if (t == 0) flag[0] = (s[0] == 0) ? 1 : 0;   // 1 => int64
}

static __device__ __forceinline__ int eidx(const int* __restrict__ p, int is64, long long pos){
  return is64 ? p[2*pos] : p[pos];   // low word (values < 2^31, non-negative)
}

// Pre-swizzle W (fp32 [602][41]) into bf16 B-fragment layout for
// mfma_f32_16x16x32_bf16: Wf[((s*3+nt)*64+lane)*8 + j] = W[k=s*32+quad*8+j][n=nt*16+l16]
__global__ void k_wprep(const float* __restrict__ W, unsigned short* __restrict__ Wf){
  int idx = blockIdx.x * 256 + threadIdx.x;
  if (idx >= KSTEPS * 3 * 64) return;
  int lane = idx & 63;
  int nt = (idx >> 6) % 3;
  int s = idx / (3 * 64);
  int quad = lane >> 4, l16 = lane & 15;
  int n = nt * 16 + l16;
  unsigned int w[4];
  #pragma unroll
  for (int p = 0; p < 4; p++){
    int k0 = s * 32 + quad * 8 + 2 * p;
    float lo = (k0     < F && n < C) ? W[k0 * C + n]       : 0.f;
    float hi = (k0 + 1 < F && n < C) ? W[(k0 + 1) * C + n] : 0.f;
    w[p] = (unsigned)f2bf(lo) | ((unsigned)f2bf(hi) << 16);
  }
  ((uint4*)Wf)[idx] = make_uint4(w[0], w[1], w[2], w[3]);
}

// FUSED front kernel: block-role split so the atomic-latency-bound count pass
// hides under the HBM-bound GEMM stream (they are independent until k_agg).
// Roles interleaved 4 count : 1 gemm (matches 12500:3125 block counts).
//
// Count role: 8-way replicated counters cnt8[r=e&7][d] -- splits the ~512
// atomics-per-128B-line serialization at the coherence point across 8 lines
// in 8 separate 800 KB regions (round-1 evidence: removing one such atomic
// pass was worth ~190 us).
//
// Gemm role: LDS-free direct-load MFMA. Wave wv owns rows [g*64+wv*16, +16);
// lane l16 = row, quad = k-subslice. Per K-step each lane loads 8 fp32
// (4x float2 -- rows are only 8-B aligned since F*4=2408), converts to bf16
// in-reg, 3 MFMAs against the L2-hot 58 KB Wf table. K-tail (602..607) is
// zeroed by special-casing step 18 / quad 3 (also avoids OOB on last row).
__global__ __launch_bounds__(256) void k_front(const float* __restrict__ x,
        const unsigned short* __restrict__ Wf, unsigned short* __restrict__ hp,
        const int* __restrict__ ei, const int* __restrict__ flag,
        int* __restrict__ cnt8, int* __restrict__ epos,
        int N, int E, int nb_e, int nb_g){
  const int bid = blockIdx.x;
  const int g = bid / 5, r5 = bid - g * 5;
  if (r5 < 4){
    // ---- count role ----
    int cb = g * 4 + r5;
    int e = cb * 256 + threadIdx.x;
    if (cb >= nb_e || e >= E) return;
    int is64 = flag[0];
    int d = eidx(ei, is64, (long long)E + e);
    int rr = e & 7;
    epos[e] = atomicAdd(&cnt8[(size_t)rr * N + d], 1);
    return;
  }
  // ---- gemm role, tile g ----
  if (g >= nb_g) return;
  const int t = threadIdx.x;
  const int wv = t >> 6, lane = t & 63;
  const int quad = lane >> 4, l16 = lane & 15;
  const long long rb0 = (long long)g * GROWS;
  long long rowb = rb0 + wv * 16 + l16;
  long long row = (rowb < N) ? rowb : (long long)(N - 1);
  const float* xr = x + row * (long long)F;
  const short8* wf8 = (const short8*)Wf;
  const int kq = quad * 8;
  f32x4 acc0 = {0.f,0.f,0.f,0.f}, acc1 = acc0, acc2 = acc0;
  #pragma unroll
  for (int s = 0; s < KSTEPS; s++){
    float xv0, xv1, xv2, xv3, xv4, xv5, xv6, xv7;
    if (s < KSTEPS - 1 || quad < 3){
      int k0 = s * 32 + kq;
      f32x2 p0 = __builtin_nontemporal_load((const f32x2*)(xr + k0 + 0));
      f32x2 p1 = __builtin_nontemporal_load((const f32x2*)(xr + k0 + 2));
      f32x2 p2 = __builtin_nontemporal_load((const f32x2*)(xr + k0 + 4));
      f32x2 p3 = __builtin_nontemporal_load((const f32x2*)(xr + k0 + 6));
      xv0 = p0[0]; xv1 = p0[1]; xv2 = p1[0]; xv3 = p1[1];
      xv4 = p2[0]; xv5 = p2[1]; xv6 = p3[0]; xv7 = p3[1];
    } else {
      // s == 18, quad == 3: k = 600..607; only 600,601 exist (also last row's end)
      f32x2 p0 = __builtin_nontemporal_load((const f32x2*)(xr + 600));
      xv0 = p0[0]; xv1 = p0[1];
      xv2 = 0.f; xv3 = 0.f; xv4 = 0.f; xv5 = 0.f; xv6 = 0.f; xv7 = 0.f;
    }
    short8 a;
    a[0] = (short)f2bf(xv0); a[1] = (short)f2bf(xv1);
    a[2] = (short)f2bf(xv2); a[3] = (short)f2bf(xv3);
    a[4] = (short)f2bf(xv4); a[5] = (short)f2bf(xv5);
    a[6] = (short)f2bf(xv6); a[7] = (short)f2bf(xv7);
    short8 b0 = wf8[(s * 3 + 0) * 64 + lane];
    short8 b1 = wf8[(s * 3 + 1) * 64 + lane];
    short8 b2 = wf8[(s * 3 + 2) * 64 + lane];
    acc0 = __builtin_amdgcn_mfma_f32_16x16x32_bf16(a, b0, acc0, 0, 0, 0);
    acc1 = __builtin_amdgcn_mfma_f32_16x16x32_bf16(a, b1, acc1, 0, 0, 0);
    acc2 = __builtin_amdgcn_mfma_f32_16x16x32_bf16(a, b2, acc2, 0, 0, 0);
  }
  // epilogue: C/D layout col=lane&15, row=quad*4+reg  [m89-verified]
  int rl = wv * 16 + quad * 4;
  #pragma unroll
  for (int reg = 0; reg < 4; reg++){
    long long grow = rb0 + rl + reg;
    if (grow < N){
      unsigned short* hr = hp + grow * HP_STRIDE;
      hr[0 * 16 + l16] = f2bf(acc0[reg]);
      hr[1 * 16 + l16] = f2bf(acc1[reg]);
      hr[2 * 16 + l16] = f2bf(acc2[reg]);
    }
  }
}

// block scans 2048 node-totals (8/thread). Per node: sum the 8 replicas,
// emit intra-node per-replica exclusive offsets (rsoff8) + dinv.
__global__ void k_scan1(const int* __restrict__ cnt8, int* __restrict__ rs,
                        float* __restrict__ dinv, int* __restrict__ rsoff8,
                        int* __restrict__ bsum, int N){
  __shared__ int s[256];
  int t = threadIdx.x;
  int base = blockIdx.x * 2048 + t * 8;
  int v[8]; int tot = 0;
  #pragma unroll
  for (int j = 0; j < 8; j++){
    int i = base + j;
    int c = 0;
    if (i < N){
      int run = 0;
      #pragma unroll
      for (int r = 0; r < 8; r++){
        int cr = cnt8[(size_t)r * N + i];
        rsoff8[(size_t)i * 8 + r] = run;
        run += cr;
      }
      c = run;
      dinv[i] = rsqrtf((float)(c + 1));
    }
    v[j] = c; tot += c;
  }
  s[t] = tot; __syncthreads();
  for (int off = 1; off < 256; off <<= 1){
    int x = (t >= off) ? s[t - off] : 0;
    __syncthreads();
    s[t] += x;
    __syncthreads();
  }
  int run = s[t] - tot;  // exclusive prefix of this thread
  #pragma unroll
  for (int j = 0; j < 8; j++){
    int i = base + j;
    if (i < N) rs[i] = run;
    run += v[j];
  }
  if (t == 255) bsum[blockIdx.x] = s[255];
}

// merged scan2+scan3: every block redundantly prefix-scans the <=256 block
// sums in LDS (trivial), then adds the offset to its 256 rs entries.
__global__ void k_scan3(int* __restrict__ rs, const int* __restrict__ bsum,
                        int N, int E, int nb){
  __shared__ int sb[256];
  __shared__ int ex[256];
  int t = threadIdx.x;
  int v = (t < nb) ? bsum[t] : 0;
  sb[t] = v; __syncthreads();
  for (int off = 1; off < 256; off <<= 1){
    int x = (t >= off) ? sb[t - off] : 0;
    __syncthreads();
    sb[t] += x;
    __syncthreads();
  }
  ex[t] = sb[t] - v;   // exclusive
  __syncthreads();
  int i = blockIdx.x * 256 + t;
  if (i == 0) rs[N] = E;
  if (i < N) rs[i] += ex[i >> 11];
}

// csr holds src only (4 B/edge); slot = rs[d] + rsoff8[d][e&7] + epos[e].
// NO atomics. rs/rsoff8 gathers are L2/L3-resident.
__global__ void k_fill(const int* __restrict__ ei, const int* __restrict__ flag,
                       const int* __restrict__ epos, const int* __restrict__ rs,
                       const int* __restrict__ rsoff8, int* __restrict__ csr, int E){
  int e = blockIdx.x * 256 + threadIdx.x;
  if (e >= E) return;
  int is64 = flag[0];
  int s = eidx(ei, is64, e);
  int d = eidx(ei, is64, (long long)E + e);
  int rr = e & 7;
  csr[rs[d] + rsoff8[(size_t)d * 8 + rr] + epos[e]] = s;
}

// one wave per node; lanes 0..40 = classes. Gather h[src] rows (1 aligned
// 128-B line each), fp32 accumulate, then FUSED bias + log_softmax epilogue.
// norm = dinv[src]*dinv[dst] recomputed here (dinv is 800 KB, L2-resident).
__global__ __launch_bounds__(256) void k_agg(const unsigned short* __restrict__ hp,
        const int* __restrict__ csr, const int* __restrict__ rs,
        const float* __restrict__ dinv, const float* __restrict__ b,
        float* __restrict__ agg, float* __restrict__ z, int N){
  int node = blockIdx.x * 4 + (threadIdx.x >> 6);
  int lane = threadIdx.x & 63;
  if (node >= N) return;
  int beg = rs[node], end = rs[node + 1];
  float dn = dinv[node];
  bool act = lane < C;
  const unsigned short* hb = hp + lane;           // row r at hb[r<<6]
  float acc = 0.f;
  if (act) acc = dn * dn * bf2f(hb[(long long)node << 6]);  // self-loop
  int i = beg;
  for (; i + 7 < end; i += 8){
    int s0 = csr[i],   s1 = csr[i+1], s2 = csr[i+2], s3 = csr[i+3];
    int s4 = csr[i+4], s5 = csr[i+5], s6 = csr[i+6], s7 = csr[i+7];
    float n0 = dinv[s0] * dn, n1 = dinv[s1] * dn;
    float n2 = dinv[s2] * dn, n3 = dinv[s3] * dn;
    float n4 = dinv[s4] * dn, n5 = dinv[s5] * dn;
    float n6 = dinv[s6] * dn, n7 = dinv[s7] * dn;
    float h0 = 0.f, h1 = 0.f, h2 = 0.f, h3 = 0.f;
    float h4 = 0.f, h5 = 0.f, h6 = 0.f, h7 = 0.f;
    if (act){
      h0 = bf2f(hb[(long long)s0 << 6]);
      h1 = bf2f(hb[(long long)s1 << 6]);
      h2 = bf2f(hb[(long long)s2 << 6]);
      h3 = bf2f(hb[(long long)s3 << 6]);
      h4 = bf2f(hb[(long long)s4 << 6]);
      h5 = bf2f(hb[(long long)s5 << 6]);
      h6 = bf2f(hb[(long long)s6 << 6]);
      h7 = bf2f(hb[(long long)s7 << 6]);
    }
    acc = fmaf(n0, h0, acc); acc = fmaf(n1, h1, acc);
    acc = fmaf(n2, h2, acc); acc = fmaf(n3, h3, acc);
    acc = fmaf(n4, h4, acc); acc = fmaf(n5, h5, acc);
    acc = fmaf(n6, h6, acc); acc = fmaf(n7, h7, acc);
  }
  for (; i + 3 < end; i += 4){
    int s0 = csr[i], s1 = csr[i+1], s2 = csr[i+2], s3 = csr[i+3];
    float n0 = dinv[s0] * dn, n1 = dinv[s1] * dn;
    float n2 = dinv[s2] * dn, n3 = dinv[s3] * dn;
    float h0 = 0.f, h1 = 0.f, h2 = 0.f, h3 = 0.f;
    if (act){
      h0 = bf2f(hb[(long long)s0 << 6]);
      h1 = bf2f(hb[(long long)s1 << 6]);
      h2 = bf2f(hb[(long long)s2 << 6]);
      h3 = bf2f(hb[(long long)s3 << 6]);
    }
    acc = fmaf(n0, h0, acc); acc = fmaf(n1, h1, acc);
    acc = fmaf(n2, h2, acc); acc = fmaf(n3, h3, acc);
  }
  for (; i < end; i++){
    int s0 = csr[i];
    float n0 = dinv[s0] * dn;
    if (act) acc = fmaf(n0, bf2f(hb[(long long)s0 << 6]), acc);
  }
  // ---- fused epilogue: bias, agg write, log_softmax, z write ----
  float a = -3.0e38f;
  if (act){
    a = acc + b[lane];
    agg[(long long)node * C + lane] = a;
  }
  float m = a;
  #pragma unroll
  for (int off = 32; off > 0; off >>= 1) m = fmaxf(m, __shfl_xor(m, off, 64));
  float ex = act ? expf(a - m) : 0.f;
  float s = ex;
  #pragma unroll
  for (int off = 32; off > 0; off >>= 1) s += __shfl_xor(s, off, 64);
  if (act) z[(long long)node * C + lane] = a - m - logf(s);
}

extern "C" void kernel_launch(void* const* d_in, const int* in_sizes, int n_in,
                              void* d_out, int out_size, void* d_ws, size_t ws_size,
                              hipStream_t stream){
  const float* x = (const float*)d_in[0];
  const float* W = (const float*)d_in[1];
  const float* b = (const float*)d_in[2];
  const int*   ei = (const int*)d_in[3];
  int N = in_sizes[0] / F;   // 200000
  int E = in_sizes[3] / 2;   // 3200000

  float* out = (float*)d_out;
  float* agg = out;
  float* z   = out + (long long)N * C;

  char* ws = (char*)d_ws;
  auto al = [](size_t v){ return (v + 255) & ~size_t(255); };
  size_t o = 0;
  int*   flag   = (int*)(ws + o);  o = al(o + 4);
  int*   cnt8   = (int*)(ws + o);  o = al(o + (size_t)N * 8 * 4);
  float* dinv   = (float*)(ws + o); o = al(o + (size_t)N * 4);
  int*   rs     = (int*)(ws + o);  o = al(o + ((size_t)N + 1) * 4);
  int*   rsoff8 = (int*)(ws + o);  o = al(o + (size_t)N * 8 * 4);
  int*   bsum   = (int*)(ws + o);  o = al(o + 4096);
  unsigned short* Wf = (unsigned short*)(ws + o); o = al(o + (size_t)KSTEPS * 3 * 64 * 16);
  int*   epos   = (int*)(ws + o);  o = al(o + (size_t)E * 4);
  int*   csr    = (int*)(ws + o);  o = al(o + (size_t)E * 4);
  unsigned short* hp = (unsigned short*)(ws + o); o = al(o + (size_t)N * HP_STRIDE * 2);

  int nb_e    = (E + 255) / 256;               // 12500
  int nb_g    = (N + GROWS - 1) / GROWS;       // 3125
  int nb_scan = (N + 2047) / 2048;             // 98 (must be <= 256)
  int nb_n    = (N + 255) / 256;
  int nb_node = (N + 3) / 4;
  int nb_w    = (KSTEPS * 3 * 64 + 255) / 256;
  int g5      = (nb_g > (nb_e + 3) / 4) ? nb_g : (nb_e + 3) / 4;

  k_flag<<<1, 256, 0, stream>>>(ei, flag);
  hipMemsetAsync(cnt8, 0, (size_t)N * 8 * 4, stream);
  k_wprep<<<nb_w, 256, 0, stream>>>(W, Wf);
  k_front<<<5 * g5, 256, 0, stream>>>(x, Wf, hp, ei, flag, cnt8, epos, N, E, nb_e, nb_g);
  k_scan1<<<nb_scan, 256, 0, stream>>>(cnt8, rs, dinv, rsoff8, bsum, N);
  k_scan3<<<nb_n, 256, 0, stream>>>(rs, bsum, N, E, nb_scan);
  k_fill<<<nb_e, 256, 0, stream>>>(ei, flag, epos, rs, rsoff8, csr, E);
  k_agg<<<nb_node, 256, 0, stream>>>(hp, csr, rs, dinv, b, agg, z, N);
}